// Round 15
// baseline (226.880 us; speedup 1.0000x reference)
//
#include <hip/hip_runtime.h>

#define N_NODES  50000
#define N_EDGES  800000
#define N_GRAPHS 512
#define HID      64
#define NCLS     5
#define NBIN     782     // ceil(N_NODES/64): one bin per 64-node layer block
#define BB       64      // binning blocks
#define EPB      (N_EDGES / BB)   // 12500 edges per binning block (exact)
#define EST      36      // LDS embed row stride in uints
#define AST      68      // LDS As row stride in uints (64 data + 4 pad)

typedef __attribute__((ext_vector_type(8))) short bf16x8;
typedef __attribute__((ext_vector_type(4))) float f32x4;

__device__ inline unsigned short f2bf(float f) {
    unsigned int u = __builtin_bit_cast(unsigned int, f);
    unsigned int r = (u + 0x7FFFu + ((u >> 16) & 1u)) >> 16;   // RNE
    return (unsigned short)r;
}
__device__ inline unsigned int packbf(float a, float b) {
    return (unsigned int)f2bf(a) | ((unsigned int)f2bf(b) << 16);
}
__device__ inline float bf2f(unsigned int u16) {
    unsigned int t = u16 << 16;
    return __builtin_bit_cast(float, t);
}

// ------- merged: bin histogram (blocks 0..63) | prep (remaining blocks) -------
#define EBUF_T (128 * 32)
#define PW_T   (64 * 64)
#define PREP_T (EBUF_T + N_NODES + 2 * PW_T)
#define PREP_B ((PREP_T + 255) / 256)
__global__ __launch_bounds__(256) void k_prep_bin1(
    const int* __restrict__ dst, int* __restrict__ hist,
    const float* __restrict__ embed, unsigned int* __restrict__ ebufg,
    const int* __restrict__ batch,
    int* __restrict__ pos_start, int* __restrict__ pos_end,
    const float* __restrict__ W1l, const float* __restrict__ W1r,
    unsigned int* __restrict__ wb1,
    const float* __restrict__ W2l, const float* __restrict__ W2r,
    unsigned int* __restrict__ wb2) {
    __shared__ int h[NBIN];
    if (blockIdx.x < BB) {
        for (int i = threadIdx.x; i < NBIN; i += 256) h[i] = 0;
        __syncthreads();
        int base = blockIdx.x * EPB;
        for (int i = threadIdx.x; i < EPB; i += 256)
            atomicAdd(&h[dst[base + i] >> 6], 1);
        __syncthreads();
        for (int i = threadIdx.x; i < NBIN; i += 256)
            hist[blockIdx.x * NBIN + i] = h[i];
        return;
    }
    int gid = (blockIdx.x - BB) * 256 + threadIdx.x;
    if (gid < EBUF_T) {
        int t = gid >> 5, c = gid & 31;
        float2 v = ((const float2*)(embed + (long)t * HID))[c];
        ebufg[gid] = packbf(v.x, v.y);
        return;
    }
    gid -= EBUF_T;
    if (gid < N_NODES) {
        int n = gid;
        int b = batch[n];
        if (n == 0 || batch[n - 1] != b) pos_start[b] = n;
        if (n == N_NODES - 1 || batch[n + 1] != b) pos_end[b] = n + 1;
        return;
    }
    gid -= N_NODES;
    if (gid < 2 * PW_T) {
        const float* Wl = (gid < PW_T) ? W1l : W2l;
        const float* Wr = (gid < PW_T) ? W1r : W2r;
        unsigned int* wb = (gid < PW_T) ? wb1 : wb2;
        int i = (gid < PW_T) ? gid : gid - PW_T;
        int h2 = i >> 6, c = i & 63;   // row h: uints 0..31 = Wl, 32..63 = Wr
        float2 v = (c < 32) ? ((const float2*)(Wl + (long)h2 * HID))[c]
                            : ((const float2*)(Wr + (long)h2 * HID))[c - 32];
        wb[i] = packbf(v.x, v.y);
    }
}

// ------- scan: hist[64][782] -> per-(block,bin) bases + bin offsets/counts -------
__global__ __launch_bounds__(1024) void k_scan(
    const int* __restrict__ hist, int* __restrict__ bbase,
    int* __restrict__ bin_off, int* __restrict__ bin_cnt) {
    __shared__ int sh[1024];
    int j = threadIdx.x;
    int run = 0;
    if (j < NBIN) {
#pragma unroll 8
        for (int b = 0; b < BB; ++b) {
            bbase[b * NBIN + j] = run;        // local (within-bin) prefix
            run += hist[b * NBIN + j];
        }
    }
    sh[j] = (j < NBIN) ? run : 0;
    __syncthreads();
    for (int o = 1; o < 1024; o <<= 1) {
        int t = (j >= o) ? sh[j - o] : 0;
        __syncthreads();
        sh[j] += t;
        __syncthreads();
    }
    if (j < NBIN) {
        int off = sh[j] - run;                // exclusive over bins
        bin_off[j] = off;
        bin_cnt[j] = run;
#pragma unroll 8
        for (int b = 0; b < BB; ++b) bbase[b * NBIN + j] += off;
    }
}

// ------- bin2: place edges into contiguous per-bin segments (no global atomics) -------
// entry = tok<<22 | (dst&63)<<16 | src  (tok<128, src<65536)
__global__ __launch_bounds__(256) void k_bin2(
    const int* __restrict__ src, const int* __restrict__ dst,
    const int* __restrict__ tok, const int* __restrict__ bbase,
    unsigned int* __restrict__ ebin) {
    __shared__ int base[NBIN];
    __shared__ int cur[NBIN];
    for (int i = threadIdx.x; i < NBIN; i += 256) {
        base[i] = bbase[blockIdx.x * NBIN + i];
        cur[i] = 0;
    }
    __syncthreads();
    int eb = blockIdx.x * EPB;
    for (int i = threadIdx.x; i < EPB; i += 256) {
        int s = src[eb + i], d = dst[eb + i];
        unsigned int t = (unsigned int)tok[s];       // L2-hot 200KB gather
        int bin = d >> 6;
        int pos = atomicAdd(&cur[bin], 1);           // LDS atomic
        ebin[base[bin] + pos] =
            (unsigned int)s | ((unsigned int)(d & 63) << 16) | (t << 22);
    }
}

// ------- fused layer: 1024-thr block = 16 waves = 64 nodes (one bin) --------
// Phase 0: read bin's contiguous edge segment, LDS-scatter into lbucket.
// Phase A (full TLP): wave aggregates 4 nodes (gather-mean from LDS bucket)
// into bf16 LDS rows; e8==1 lanes stage the self row ([agg | x_self], K=128).
// Phase B: wave -> 16-node strip x 16-h tile; 4 MFMAs (C^T), ushort4 store.
template <bool L1>
__global__ __launch_bounds__(1024) void k_layer(
    const int* __restrict__ bin_off, const int* __restrict__ bin_cnt,
    const unsigned int* __restrict__ ebin,
    const int* __restrict__ tok, const unsigned int* __restrict__ ebufg,
    const unsigned int* __restrict__ xb,
    const unsigned int* __restrict__ wb, const float* __restrict__ bl,
    unsigned short* __restrict__ xoutb)
{
    __shared__ unsigned int As[64 * AST];
    __shared__ unsigned int lbucket[64 * 64];
    __shared__ int lcnt[64];
    __shared__ unsigned int elds[L1 ? 128 * EST : 1];
    const int tid  = threadIdx.x;
    const int wv   = tid >> 6;        // 0..15
    const int lane = tid & 63;
    const int n0   = blockIdx.x * 64;

    if (tid < 64) lcnt[tid] = 0;
    if (L1) {
        for (int i = tid; i < EBUF_T; i += 1024) {
            int t = i >> 5, c = i & 31;
            elds[t * EST + c] = ebufg[i];
        }
    }
    __syncthreads();

    // Phase 0: coalesced segment read + LDS scatter
    {
        int boffv = bin_off[blockIdx.x];
        int bcnt  = bin_cnt[blockIdx.x];
        for (int i = tid; i < bcnt; i += 1024) {
            unsigned int v = ebin[boffv + i];
            int dl = (v >> 16) & 63;
            int pos = atomicAdd(&lcnt[dl], 1);
            if (pos < 64) lbucket[dl * 64 + pos] = v;
        }
    }
    __syncthreads();

    const int q  = lane & 7;          // 16B chunk (channels 8q..8q+7)
    const int e8 = lane >> 3;         // edge slot within group of 8

#pragma unroll
    for (int i = 0; i < 4; ++i) {
        int rl = wv * 4 + i;          // local row 0..63
        int nn = n0 + rl;
        int nc = min(nn, N_NODES - 1);
        int deg = lcnt[rl];
        int m   = min(deg, 64);
        unsigned int v = (lane < m) ? lbucket[rl * 64 + lane] : 0u;
        float f0 = 0, f1 = 0, f2 = 0, f3 = 0, f4 = 0, f5 = 0, f6 = 0, f7 = 0;
#pragma unroll
        for (int g = 0; g < 8; ++g) {
            int j = g * 8 + e8;
            unsigned int vv = __shfl(v, j, 64);
            if (j < m) {
                uint4 w4;
                if (L1) w4 = *(const uint4*)(elds + (vv >> 22) * EST + q * 4);
                else    w4 = *((const uint4*)(xb + (long)(vv & 0xffffu) * 32) + q);
                f0 += bf2f(w4.x & 0xffff); f1 += bf2f(w4.x >> 16);
                f2 += bf2f(w4.y & 0xffff); f3 += bf2f(w4.y >> 16);
                f4 += bf2f(w4.z & 0xffff); f5 += bf2f(w4.z >> 16);
                f6 += bf2f(w4.w & 0xffff); f7 += bf2f(w4.w >> 16);
            }
        }
#pragma unroll
        for (int o = 8; o < 64; o <<= 1) {
            f0 += __shfl_xor(f0, o, 64); f1 += __shfl_xor(f1, o, 64);
            f2 += __shfl_xor(f2, o, 64); f3 += __shfl_xor(f3, o, 64);
            f4 += __shfl_xor(f4, o, 64); f5 += __shfl_xor(f5, o, 64);
            f6 += __shfl_xor(f6, o, 64); f7 += __shfl_xor(f7, o, 64);
        }
        if (e8 == 0) {
            float inv = 1.0f / (float)max(deg, 1);
            uint4 o;
            o.x = packbf(f0 * inv, f1 * inv);
            o.y = packbf(f2 * inv, f3 * inv);
            o.z = packbf(f4 * inv, f5 * inv);
            o.w = packbf(f6 * inv, f7 * inv);
            *(uint4*)(As + rl * AST + q * 4) = o;
        } else if (e8 == 1) {
            uint4 sv;
            if (L1) { int tk = tok[nc]; sv = *(const uint4*)(elds + tk * EST + q * 4); }
            else    { sv = *((const uint4*)(xb + (long)nc * 32) + q); }
            *(uint4*)(As + rl * AST + 32 + q * 4) = sv;
        }
    }
    __syncthreads();

    // Phase B: wave wv -> strip s = wv&3 (16 nodes), h-tile t = wv>>2
    const int s    = wv & 3;
    const int t    = wv >> 2;
    const int mm   = lane & 15;
    const int quad = lane >> 4;

    bf16x8 afr[4];
#pragma unroll
    for (int kst = 0; kst < 4; ++kst)
        afr[kst] = *(const bf16x8*)(As + (s * 16 + mm) * AST + kst * 16 + quad * 4);

    f32x4 acc = (f32x4){0.f, 0.f, 0.f, 0.f};
#pragma unroll
    for (int kst = 0; kst < 4; ++kst) {
        bf16x8 bfr = *(const bf16x8*)(wb + (t * 16 + mm) * 64 + kst * 16 + quad * 4);
        acc = __builtin_amdgcn_mfma_f32_16x16x32_bf16(bfr, afr[kst], acc, 0, 0, 0);
    }

    // C^T[h][node]: h = t*16 + quad*4 + r, node = n0 + s*16 + mm
    int node = n0 + s * 16 + mm;
    if (node < N_NODES) {
        int hb = t * 16 + quad * 4;
        float4 bb = *(const float4*)(bl + hb);
        ushort4 o;
        o.x = f2bf(fmaxf(acc[0] + bb.x, 0.f));
        o.y = f2bf(fmaxf(acc[1] + bb.y, 0.f));
        o.z = f2bf(fmaxf(acc[2] + bb.z, 0.f));
        o.w = f2bf(fmaxf(acc[3] + bb.w, 0.f));
        *(ushort4*)(xoutb + (long)node * HID + hb) = o;
    }
}

// ------- pool + head: one wave per graph; batch sorted -> contiguous node range -------
__global__ __launch_bounds__(64) void k_pool(
    const unsigned int* __restrict__ x2b,
    const int* __restrict__ pos_start, const int* __restrict__ pos_end,
    const float* __restrict__ Wlin, const float* __restrict__ blin,
    float* __restrict__ out)
{
    int g    = blockIdx.x;
    int lane = threadIdx.x;
    int q    = lane & 7;     // 16B chunk (channels 8q..8q+7)
    int slot = lane >> 3;    // node slot within group of 8
    int s = pos_start[g], e = pos_end[g];
    float f0 = 0, f1 = 0, f2 = 0, f3 = 0, f4 = 0, f5 = 0, f6 = 0, f7 = 0;
    for (int n = s + slot; n < e; n += 8) {
        uint4 v = *((const uint4*)(x2b + (long)n * 32) + q);
        f0 += bf2f(v.x & 0xffff); f1 += bf2f(v.x >> 16);
        f2 += bf2f(v.y & 0xffff); f3 += bf2f(v.y >> 16);
        f4 += bf2f(v.z & 0xffff); f5 += bf2f(v.z >> 16);
        f6 += bf2f(v.w & 0xffff); f7 += bf2f(v.w >> 16);
    }
#pragma unroll
    for (int o = 8; o < 64; o <<= 1) {
        f0 += __shfl_xor(f0, o, 64); f1 += __shfl_xor(f1, o, 64);
        f2 += __shfl_xor(f2, o, 64); f3 += __shfl_xor(f3, o, 64);
        f4 += __shfl_xor(f4, o, 64); f5 += __shfl_xor(f5, o, 64);
        f6 += __shfl_xor(f6, o, 64); f7 += __shfl_xor(f7, o, 64);
    }
    float inv = 1.0f / (float)max(e - s, 1);
    f0 *= inv; f1 *= inv; f2 *= inv; f3 *= inv;
    f4 *= inv; f5 *= inv; f6 *= inv; f7 *= inv;
#pragma unroll
    for (int c = 0; c < NCLS; ++c) {
        const float* wr = Wlin + c * HID + q * 8;
        float p = f0 * wr[0] + f1 * wr[1] + f2 * wr[2] + f3 * wr[3] +
                  f4 * wr[4] + f5 * wr[5] + f6 * wr[6] + f7 * wr[7];
        p += __shfl_xor(p, 1, 64);
        p += __shfl_xor(p, 2, 64);
        p += __shfl_xor(p, 4, 64);
        if (lane == 0) out[g * NCLS + c] = p + blin[c];
    }
}

extern "C" void kernel_launch(void* const* d_in, const int* in_sizes, int n_in,
                              void* d_out, int out_size, void* d_ws, size_t ws_size,
                              hipStream_t stream) {
    const int*   tok   = (const int*)d_in[0];
    const int*   eidx  = (const int*)d_in[1];
    const int*   batch = (const int*)d_in[2];
    const float* embed = (const float*)d_in[3];
    const float* W1l   = (const float*)d_in[4];
    const float* b1l   = (const float*)d_in[5];
    const float* W1r   = (const float*)d_in[6];
    const float* W2l   = (const float*)d_in[7];
    const float* b2l   = (const float*)d_in[8];
    const float* W2r   = (const float*)d_in[9];
    const float* Wlin  = (const float*)d_in[10];
    const float* blin  = (const float*)d_in[11];
    float* out = (float*)d_out;

    const int* src = eidx;
    const int* dst = eidx + N_EDGES;

    char* wsp = (char*)d_ws;
    size_t off = 0;
    auto alloc = [&](size_t bytes) -> void* {
        void* p = wsp + off;
        off = (off + bytes + 255) & ~(size_t)255;
        return p;
    };
    // pstart | pend adjacent -> single small memset
    int*   pstart  = (int*)  alloc((size_t)N_GRAPHS * 4);
    int*   pend    = (int*)  alloc((size_t)N_GRAPHS * 4);
    int*   hist    = (int*)  alloc((size_t)BB * NBIN * 4);
    int*   bbase   = (int*)  alloc((size_t)BB * NBIN * 4);
    int*   bin_off = (int*)  alloc((size_t)NBIN * 4);
    int*   bin_cnt = (int*)  alloc((size_t)NBIN * 4);
    unsigned int* ebin  = (unsigned int*)alloc((size_t)N_EDGES * 4);
    unsigned int* x1b   = (unsigned int*)alloc((size_t)N_NODES * 32 * 4);
    unsigned int* x2b   = (unsigned int*)alloc((size_t)N_NODES * 32 * 4);
    unsigned int* ebufg = (unsigned int*)alloc((size_t)128 * 32 * 4);
    unsigned int* wb1   = (unsigned int*)alloc((size_t)64 * 64 * 4);
    unsigned int* wb2   = (unsigned int*)alloc((size_t)64 * 64 * 4);

    hipMemsetAsync(pstart, 0, (char*)pend - (char*)pstart + (size_t)N_GRAPHS * 4, stream);

    // blocks 0..63: bin histogram; remaining: prep
    k_prep_bin1<<<BB + PREP_B, 256, 0, stream>>>(
        dst, hist, embed, ebufg, batch, pstart, pend,
        W1l, W1r, wb1, W2l, W2r, wb2);

    k_scan<<<1, 1024, 0, stream>>>(hist, bbase, bin_off, bin_cnt);
    k_bin2<<<BB, 256, 0, stream>>>(src, dst, tok, bbase, ebin);

    const int LBLK = NBIN;   // == (N_NODES + 63) / 64
    // Layer 1: neighbors+self from LDS embed table (via tok in ebin / tok[n])
    k_layer<true><<<LBLK, 1024, 0, stream>>>(bin_off, bin_cnt, ebin, tok, ebufg,
                                             nullptr, wb1, b1l, (unsigned short*)x1b);
    // Layer 2: neighbors+self from x1b
    k_layer<false><<<LBLK, 1024, 0, stream>>>(bin_off, bin_cnt, ebin, nullptr, nullptr,
                                              x1b, wb2, b2l, (unsigned short*)x2b);

    // Pool + head
    k_pool<<<N_GRAPHS, 64, 0, stream>>>(x2b, pstart, pend, Wlin, blin, out);
}

// Round 16
// 206.300 us; speedup vs baseline: 1.0998x; 1.0998x over previous
//
#include <hip/hip_runtime.h>

#define N_NODES  50000
#define N_EDGES  800000
#define N_GRAPHS 512
#define HID      64
#define NCLS     5
#define NB       64      // bucket capacity per node (max deg ~40 for this graph)
#define EST      36      // LDS embed row stride in uints
#define AST      68      // LDS As row stride in uints (64 data + 4 pad)

typedef __attribute__((ext_vector_type(8))) short bf16x8;
typedef __attribute__((ext_vector_type(4))) float f32x4;

__device__ inline unsigned short f2bf(float f) {
    unsigned int u = __builtin_bit_cast(unsigned int, f);
    unsigned int r = (u + 0x7FFFu + ((u >> 16) & 1u)) >> 16;   // RNE
    return (unsigned short)r;
}
__device__ inline unsigned int packbf(float a, float b) {
    return (unsigned int)f2bf(a) | ((unsigned int)f2bf(b) << 16);
}
__device__ inline float bf2f(unsigned int u16) {
    unsigned int t = u16 << 16;
    return __builtin_bit_cast(float, t);
}

// ------- merged prep+fill (NORMAL stores — R13's nt-store was the poison) -------
// gid 0..N_EDGES: bucket fill (cnt atomic + (tok<<16|src) slot store, L2-cached)
// then: embed-pack | batch boundaries | pack W1/W2
#define EBUF_T (128 * 32)
#define PW_T   (64 * 64)
#define PREP_T (N_EDGES + EBUF_T + N_NODES + 2 * PW_T)
__global__ void k_prep_fill(
    const int* __restrict__ src, const int* __restrict__ dst,
    const int* __restrict__ tok,
    int* __restrict__ cnt, unsigned int* __restrict__ bucket,
    const float* __restrict__ embed, unsigned int* __restrict__ ebufg,
    const int* __restrict__ batch,
    int* __restrict__ pos_start, int* __restrict__ pos_end,
    const float* __restrict__ W1l, const float* __restrict__ W1r,
    unsigned int* __restrict__ wb1,
    const float* __restrict__ W2l, const float* __restrict__ W2r,
    unsigned int* __restrict__ wb2) {
    int gid = blockIdx.x * blockDim.x + threadIdx.x;
    if (gid < N_EDGES) {
        int s = src[gid], d = dst[gid];
        unsigned int t = (unsigned int)tok[s];         // L2-hot 200KB gather
        int pos = atomicAdd(&cnt[d], 1);
        if (pos < NB) bucket[(long)d * NB + pos] = (unsigned int)s | (t << 16);
        return;
    }
    gid -= N_EDGES;
    if (gid < EBUF_T) {
        int t = gid >> 5, c = gid & 31;
        float2 v = ((const float2*)(embed + (long)t * HID))[c];
        ebufg[gid] = packbf(v.x, v.y);
        return;
    }
    gid -= EBUF_T;
    if (gid < N_NODES) {
        int n = gid;
        int b = batch[n];
        if (n == 0 || batch[n - 1] != b) pos_start[b] = n;
        if (n == N_NODES - 1 || batch[n + 1] != b) pos_end[b] = n + 1;
        return;
    }
    gid -= N_NODES;
    if (gid < 2 * PW_T) {
        const float* Wl = (gid < PW_T) ? W1l : W2l;
        const float* Wr = (gid < PW_T) ? W1r : W2r;
        unsigned int* wb = (gid < PW_T) ? wb1 : wb2;
        int i = (gid < PW_T) ? gid : gid - PW_T;
        int h = i >> 6, c = i & 63;   // row h: uints 0..31 = Wl, 32..63 = Wr
        float2 v = (c < 32) ? ((const float2*)(Wl + (long)h * HID))[c]
                            : ((const float2*)(Wr + (long)h * HID))[c - 32];
        wb[i] = packbf(v.x, v.y);
    }
}

// ------- fused layer: 1024-thr block = 16 waves = 64 nodes (R12 version) ----
// Phase A (full TLP): wave aggregates 4 nodes (gather-mean from bucket) into
// bf16 LDS rows; e8==1 lanes stage the self row ([agg | x_self], K=128).
// Phase B (one barrier): wave -> 16-node strip x 16-h tile; 4 MFMAs (C^T),
// one ushort4 full-line store per lane.
// L1: neighbor/self features from LDS embed table via tok; L2: from global xb.
template <bool L1>
__global__ __launch_bounds__(1024) void k_layer(
    const int* __restrict__ cnt, const unsigned int* __restrict__ bucket,
    const int* __restrict__ tok, const unsigned int* __restrict__ ebufg,
    const unsigned int* __restrict__ xb,
    const unsigned int* __restrict__ wb, const float* __restrict__ bl,
    unsigned short* __restrict__ xoutb)
{
    __shared__ unsigned int As[64 * AST];
    __shared__ unsigned int elds[L1 ? 128 * EST : 1];
    const int tid  = threadIdx.x;
    const int wv   = tid >> 6;        // 0..15
    const int lane = tid & 63;
    const int n0   = blockIdx.x * 64;

    if (L1) {
        for (int i = tid; i < EBUF_T; i += 1024) {
            int t = i >> 5, c = i & 31;
            elds[t * EST + c] = ebufg[i];
        }
        __syncthreads();
    }

    const int q  = lane & 7;          // 16B chunk (channels 8q..8q+7)
    const int e8 = lane >> 3;         // edge slot within group of 8

#pragma unroll
    for (int i = 0; i < 4; ++i) {
        int rl = wv * 4 + i;          // local row 0..63
        int nn = n0 + rl;
        int nc = min(nn, N_NODES - 1);
        int deg = cnt[nc];
        int m   = (nn < N_NODES) ? min(deg, NB) : 0;
        unsigned int v = (lane < m) ? bucket[(long)nc * NB + lane] : 0u;
        float f0 = 0, f1 = 0, f2 = 0, f3 = 0, f4 = 0, f5 = 0, f6 = 0, f7 = 0;
#pragma unroll
        for (int g = 0; g < 8; ++g) {
            int j = g * 8 + e8;
            unsigned int vv = __shfl(v, j, 64);
            if (j < m) {
                uint4 w4;
                if (L1) w4 = *(const uint4*)(elds + (vv >> 16) * EST + q * 4);
                else    w4 = *((const uint4*)(xb + (long)(vv & 0xffffu) * 32) + q);
                f0 += bf2f(w4.x & 0xffff); f1 += bf2f(w4.x >> 16);
                f2 += bf2f(w4.y & 0xffff); f3 += bf2f(w4.y >> 16);
                f4 += bf2f(w4.z & 0xffff); f5 += bf2f(w4.z >> 16);
                f6 += bf2f(w4.w & 0xffff); f7 += bf2f(w4.w >> 16);
            }
        }
#pragma unroll
        for (int o = 8; o < 64; o <<= 1) {
            f0 += __shfl_xor(f0, o, 64); f1 += __shfl_xor(f1, o, 64);
            f2 += __shfl_xor(f2, o, 64); f3 += __shfl_xor(f3, o, 64);
            f4 += __shfl_xor(f4, o, 64); f5 += __shfl_xor(f5, o, 64);
            f6 += __shfl_xor(f6, o, 64); f7 += __shfl_xor(f7, o, 64);
        }
        if (e8 == 0) {
            float inv = 1.0f / (float)max(deg, 1);
            uint4 o;
            o.x = packbf(f0 * inv, f1 * inv);
            o.y = packbf(f2 * inv, f3 * inv);
            o.z = packbf(f4 * inv, f5 * inv);
            o.w = packbf(f6 * inv, f7 * inv);
            *(uint4*)(As + rl * AST + q * 4) = o;
        } else if (e8 == 1) {
            uint4 sv;
            if (L1) { int tk = tok[nc]; sv = *(const uint4*)(elds + tk * EST + q * 4); }
            else    { sv = *((const uint4*)(xb + (long)nc * 32) + q); }
            *(uint4*)(As + rl * AST + 32 + q * 4) = sv;
        }
    }
    __syncthreads();

    // Phase B: wave wv -> strip s = wv&3 (16 nodes), h-tile t = wv>>2
    const int s    = wv & 3;
    const int t    = wv >> 2;
    const int mm   = lane & 15;
    const int quad = lane >> 4;

    bf16x8 afr[4];
#pragma unroll
    for (int kst = 0; kst < 4; ++kst)
        afr[kst] = *(const bf16x8*)(As + (s * 16 + mm) * AST + kst * 16 + quad * 4);

    f32x4 acc = (f32x4){0.f, 0.f, 0.f, 0.f};
#pragma unroll
    for (int kst = 0; kst < 4; ++kst) {
        bf16x8 bfr = *(const bf16x8*)(wb + (t * 16 + mm) * 64 + kst * 16 + quad * 4);
        acc = __builtin_amdgcn_mfma_f32_16x16x32_bf16(bfr, afr[kst], acc, 0, 0, 0);
    }

    // C^T[h][node]: h = t*16 + quad*4 + r, node = n0 + s*16 + mm
    int node = n0 + s * 16 + mm;
    if (node < N_NODES) {
        int hb = t * 16 + quad * 4;
        float4 bb = *(const float4*)(bl + hb);
        ushort4 o;
        o.x = f2bf(fmaxf(acc[0] + bb.x, 0.f));
        o.y = f2bf(fmaxf(acc[1] + bb.y, 0.f));
        o.z = f2bf(fmaxf(acc[2] + bb.z, 0.f));
        o.w = f2bf(fmaxf(acc[3] + bb.w, 0.f));
        *(ushort4*)(xoutb + (long)node * HID + hb) = o;
    }
}

// ------- pool + head: one wave per graph; batch sorted -> contiguous node range -------
__global__ __launch_bounds__(64) void k_pool(
    const unsigned int* __restrict__ x2b,
    const int* __restrict__ pos_start, const int* __restrict__ pos_end,
    const float* __restrict__ Wlin, const float* __restrict__ blin,
    float* __restrict__ out)
{
    int g    = blockIdx.x;
    int lane = threadIdx.x;
    int q    = lane & 7;     // 16B chunk (channels 8q..8q+7)
    int slot = lane >> 3;    // node slot within group of 8
    int s = pos_start[g], e = pos_end[g];
    float f0 = 0, f1 = 0, f2 = 0, f3 = 0, f4 = 0, f5 = 0, f6 = 0, f7 = 0;
    for (int n = s + slot; n < e; n += 8) {
        uint4 v = *((const uint4*)(x2b + (long)n * 32) + q);
        f0 += bf2f(v.x & 0xffff); f1 += bf2f(v.x >> 16);
        f2 += bf2f(v.y & 0xffff); f3 += bf2f(v.y >> 16);
        f4 += bf2f(v.z & 0xffff); f5 += bf2f(v.z >> 16);
        f6 += bf2f(v.w & 0xffff); f7 += bf2f(v.w >> 16);
    }
#pragma unroll
    for (int o = 8; o < 64; o <<= 1) {
        f0 += __shfl_xor(f0, o, 64); f1 += __shfl_xor(f1, o, 64);
        f2 += __shfl_xor(f2, o, 64); f3 += __shfl_xor(f3, o, 64);
        f4 += __shfl_xor(f4, o, 64); f5 += __shfl_xor(f5, o, 64);
        f6 += __shfl_xor(f6, o, 64); f7 += __shfl_xor(f7, o, 64);
    }
    float inv = 1.0f / (float)max(e - s, 1);
    f0 *= inv; f1 *= inv; f2 *= inv; f3 *= inv;
    f4 *= inv; f5 *= inv; f6 *= inv; f7 *= inv;
#pragma unroll
    for (int c = 0; c < NCLS; ++c) {
        const float* wr = Wlin + c * HID + q * 8;
        float p = f0 * wr[0] + f1 * wr[1] + f2 * wr[2] + f3 * wr[3] +
                  f4 * wr[4] + f5 * wr[5] + f6 * wr[6] + f7 * wr[7];
        p += __shfl_xor(p, 1, 64);
        p += __shfl_xor(p, 2, 64);
        p += __shfl_xor(p, 4, 64);
        if (lane == 0) out[g * NCLS + c] = p + blin[c];
    }
}

extern "C" void kernel_launch(void* const* d_in, const int* in_sizes, int n_in,
                              void* d_out, int out_size, void* d_ws, size_t ws_size,
                              hipStream_t stream) {
    const int*   tok   = (const int*)d_in[0];
    const int*   eidx  = (const int*)d_in[1];
    const int*   batch = (const int*)d_in[2];
    const float* embed = (const float*)d_in[3];
    const float* W1l   = (const float*)d_in[4];
    const float* b1l   = (const float*)d_in[5];
    const float* W1r   = (const float*)d_in[6];
    const float* W2l   = (const float*)d_in[7];
    const float* b2l   = (const float*)d_in[8];
    const float* W2r   = (const float*)d_in[9];
    const float* Wlin  = (const float*)d_in[10];
    const float* blin  = (const float*)d_in[11];
    float* out = (float*)d_out;

    const int* src = eidx;
    const int* dst = eidx + N_EDGES;

    char* wsp = (char*)d_ws;
    size_t off = 0;
    auto alloc = [&](size_t bytes) -> void* {
        void* p = wsp + off;
        off = (off + bytes + 255) & ~(size_t)255;
        return p;
    };
    // cnt | pstart | pend adjacent -> single memset
    int*   cnt     = (int*)  alloc((size_t)N_NODES * 4);
    int*   pstart  = (int*)  alloc((size_t)N_GRAPHS * 4);
    int*   pend    = (int*)  alloc((size_t)N_GRAPHS * 4);
    unsigned int* bucket = (unsigned int*)alloc((size_t)N_NODES * NB * 4);
    unsigned int* x1b    = (unsigned int*)alloc((size_t)N_NODES * 32 * 4);
    unsigned int* x2b    = (unsigned int*)alloc((size_t)N_NODES * 32 * 4);
    unsigned int* ebufg  = (unsigned int*)alloc((size_t)128 * 32 * 4);
    unsigned int* wb1    = (unsigned int*)alloc((size_t)64 * 64 * 4);
    unsigned int* wb2    = (unsigned int*)alloc((size_t)64 * 64 * 4);

    hipMemsetAsync(cnt, 0, (char*)pend - (char*)cnt + (size_t)N_GRAPHS * 4, stream);

    k_prep_fill<<<(PREP_T + 255) / 256, 256, 0, stream>>>(
        src, dst, tok, cnt, bucket,
        embed, ebufg, batch, pstart, pend, W1l, W1r, wb1, W2l, W2r, wb2);

    const int LBLK = (N_NODES + 63) / 64;
    // Layer 1: neighbors+self from LDS embed table (via tok in bucket / tok[n])
    k_layer<true><<<LBLK, 1024, 0, stream>>>(cnt, bucket, tok, ebufg, nullptr,
                                             wb1, b1l, (unsigned short*)x1b);
    // Layer 2: neighbors+self from x1b
    k_layer<false><<<LBLK, 1024, 0, stream>>>(cnt, bucket, nullptr, nullptr, x1b,
                                              wb2, b2l, (unsigned short*)x2b);

    // Pool + head
    k_pool<<<N_GRAPHS, 64, 0, stream>>>(x2b, pstart, pend, Wlin, blin, out);
}